// Round 4
// baseline (638.866 us; speedup 1.0000x reference)
//
#include <hip/hip_runtime.h>

#define NFEAT 42
#define H1 256
#define H2 128
#define H3 64
#define NB 8
#define NA 512
#define NM 100
#define TA 8   // atoms per MLP block (grid 512 -> 2 blocks/CU, 16 waves/CU)

__device__ __forceinline__ float sigmoidf(float z) {
    return 1.0f / (1.0f + __expf(-z));
}

// -------- Kernel 0: transpose weights (write-coalesced) --------
__global__ __launch_bounds__(256) void transpose_weights(
    const float* __restrict__ W0, const float* __restrict__ W1, const float* __restrict__ W2,
    float* __restrict__ W0T, float* __restrict__ W1T, float* __restrict__ W2T)
{
    int i = blockIdx.x * 256 + threadIdx.x;
    if (i < H1 * NFEAT) {           // W0T[k][f] = W0[f][k]
        int k = i / NFEAT, f = i - k * NFEAT;
        W0T[i] = W0[f * H1 + k];
    }
    if (i < H2 * H1) {              // W1T[j][k] = W1[k][j]
        int j = i >> 8, k = i & 255;
        W1T[i] = W1[k * H2 + j];
    }
    if (i < H3 * H2) {              // W2T[k][j] = W2[j][k]
        int k = i >> 7, j = i & 127;
        W2T[i] = W2[j * H3 + k];
    }
}

// -------- Kernel 1: per-8-atom MLP fwd+bwd, weights LDS-staged in 24KB chunks --------
__global__ __launch_bounds__(256) void mlp_fwd_bwd(
    const float* __restrict__ image,
    const float* __restrict__ W0, const float* __restrict__ b0,
    const float* __restrict__ W1, const float* __restrict__ b1,
    const float* __restrict__ W2, const float* __restrict__ b2,
    const float* __restrict__ W3, const float* __restrict__ b3,
    const float* __restrict__ W0T, const float* __restrict__ W1T, const float* __restrict__ W2T,
    float* __restrict__ Ei,   // [B*N]
    float* __restrict__ dE)   // [B*N, NFEAT]
{
    const int t = threadIdx.x;
    const int atom0 = blockIdx.x * TA;

    __shared__ __align__(16) float sx[TA][NFEAT + 2];   // 44 floats/row for float4
    __shared__ __align__(16) float sh1[TA][H1];
    __shared__ __align__(16) float sh2[TA][H2];
    __shared__ __align__(16) float sh3[TA][H3];
    __shared__ __align__(16) float sd3[TA][H3];
    __shared__ __align__(16) float sd2[TA][H2];
    __shared__ __align__(16) float sd1[TA][H1];
    __shared__ __align__(16) float wbuf[6144];          // 24KB weight staging

    // cooperative stage: nf floats (nf % 4 == 0, src 16B-aligned)
    auto stage = [&](const float* src, int nf) {
        __syncthreads();                 // previous consumers done
        const float4* s4 = (const float4*)src;
        float4* d4 = (float4*)wbuf;
        int n4 = nf >> 2;
        for (int i = t; i < n4; i += 256) d4[i] = s4[i];
        __syncthreads();                 // staged data visible
    };

    for (int i = t; i < TA * NFEAT; i += 256) {
        int a = i / NFEAT, f = i - a * NFEAT;
        sx[a][f] = image[(atom0 + a) * NFEAT + f];
    }
    // (stage()'s first barrier covers the sx visibility)

    // ---- layer 0: 42 -> 256, sigmoid. thread = neuron t, 8 atoms ----
    {
        float acc[TA];
        #pragma unroll
        for (int a = 0; a < TA; ++a) acc[a] = 0.f;

        stage(W0, 24 * H1);                      // k rows 0..23
        for (int kq = 0; kq < 6; ++kq) {
            float w0_ = wbuf[(4 * kq + 0) * H1 + t];
            float w1_ = wbuf[(4 * kq + 1) * H1 + t];
            float w2_ = wbuf[(4 * kq + 2) * H1 + t];
            float w3_ = wbuf[(4 * kq + 3) * H1 + t];
            #pragma unroll
            for (int a = 0; a < TA; ++a) {
                float4 h = ((const float4*)sx[a])[kq];
                acc[a] += h.x * w0_ + h.y * w1_ + h.z * w2_ + h.w * w3_;
            }
        }
        stage(W0 + 24 * H1, 18 * H1);            // k rows 24..41
        for (int kq = 0; kq < 4; ++kq) {         // k = 24..39
            float w0_ = wbuf[(4 * kq + 0) * H1 + t];
            float w1_ = wbuf[(4 * kq + 1) * H1 + t];
            float w2_ = wbuf[(4 * kq + 2) * H1 + t];
            float w3_ = wbuf[(4 * kq + 3) * H1 + t];
            #pragma unroll
            for (int a = 0; a < TA; ++a) {
                float4 h = ((const float4*)sx[a])[6 + kq];
                acc[a] += h.x * w0_ + h.y * w1_ + h.z * w2_ + h.w * w3_;
            }
        }
        float wa = wbuf[16 * H1 + t], wb = wbuf[17 * H1 + t];   // k = 40, 41
        float bb = b0[t];
        #pragma unroll
        for (int a = 0; a < TA; ++a) {
            acc[a] += sx[a][40] * wa + sx[a][41] * wb;
            sh1[a][t] = sigmoidf(acc[a] + bb);
        }
    }

    // ---- layer 1: 256 -> 128, sigmoid. j = t&127, 4 atoms/thread ----
    {
        const int j = t & 127, a0 = (t >> 7) * 4;
        float acc[4] = {0.f, 0.f, 0.f, 0.f};
        for (int c = 0; c < 6; ++c) {
            const int k0 = 48 * c;
            const int nrow = (c < 5) ? 48 : 16;
            stage(W1 + k0 * H2, nrow * H2);
            const int q0 = k0 >> 2;
            for (int kq = 0; kq < nrow / 4; ++kq) {
                float w0_ = wbuf[(4 * kq + 0) * H2 + j];
                float w1_ = wbuf[(4 * kq + 1) * H2 + j];
                float w2_ = wbuf[(4 * kq + 2) * H2 + j];
                float w3_ = wbuf[(4 * kq + 3) * H2 + j];
                #pragma unroll
                for (int a = 0; a < 4; ++a) {
                    float4 h = ((const float4*)sh1[a0 + a])[q0 + kq];
                    acc[a] += h.x * w0_ + h.y * w1_ + h.z * w2_ + h.w * w3_;
                }
            }
        }
        float bb = b1[j];
        #pragma unroll
        for (int a = 0; a < 4; ++a) sh2[a0 + a][j] = sigmoidf(acc[a] + bb);
    }

    // ---- layer 2: 128 -> 64, sigmoid. j = t&63, 2 atoms/thread ----
    {
        const int j = t & 63, a0 = (t >> 6) * 2;
        float acc[2] = {0.f, 0.f};
        for (int c = 0; c < 2; ++c) {
            const int k0 = (c == 0) ? 0 : 96;
            const int nrow = (c == 0) ? 96 : 32;
            stage(W2 + k0 * H3, nrow * H3);
            const int q0 = k0 >> 2;
            for (int kq = 0; kq < nrow / 4; ++kq) {
                float w0_ = wbuf[(4 * kq + 0) * H3 + j];
                float w1_ = wbuf[(4 * kq + 1) * H3 + j];
                float w2_ = wbuf[(4 * kq + 2) * H3 + j];
                float w3_ = wbuf[(4 * kq + 3) * H3 + j];
                #pragma unroll
                for (int a = 0; a < 2; ++a) {
                    float4 h = ((const float4*)sh2[a0 + a])[q0 + kq];
                    acc[a] += h.x * w0_ + h.y * w1_ + h.z * w2_ + h.w * w3_;
                }
            }
        }
        float bb = b2[j];
        #pragma unroll
        for (int a = 0; a < 2; ++a) sh3[a0 + a][j] = sigmoidf(acc[a] + bb);
    }
    __syncthreads();

    // ---- output 64 -> 1 (linear) + sd3. wave w: atoms 2w, 2w+1 ----
    {
        const int lane = t & 63, a0 = (t >> 6) * 2;
        float w = W3[lane];
        float bb = b3[0];
        #pragma unroll
        for (int a = a0; a < a0 + 2; ++a) {
            float h = sh3[a][lane];
            sd3[a][lane] = w * h * (1.f - h);
            float v = w * h;
            #pragma unroll
            for (int off = 32; off > 0; off >>= 1) v += __shfl_down(v, off, 64);
            if (lane == 0) Ei[atom0 + a] = v + bb;
        }
    }

    // ---- bwd: d2 = (W2 @ d3) * h2'. j = t&127, 4 atoms/thread ----
    {
        const int j = t & 127, a0 = (t >> 7) * 4;
        float acc[4] = {0.f, 0.f, 0.f, 0.f};
        for (int c = 0; c < 2; ++c) {
            const int k0 = (c == 0) ? 0 : 48;     // rows of W2T (H3=64 rows)
            const int nrow = (c == 0) ? 48 : 16;
            stage(W2T + k0 * H2, nrow * H2);
            const int q0 = k0 >> 2;
            for (int kq = 0; kq < nrow / 4; ++kq) {
                float w0_ = wbuf[(4 * kq + 0) * H2 + j];
                float w1_ = wbuf[(4 * kq + 1) * H2 + j];
                float w2_ = wbuf[(4 * kq + 2) * H2 + j];
                float w3_ = wbuf[(4 * kq + 3) * H2 + j];
                #pragma unroll
                for (int a = 0; a < 4; ++a) {
                    float4 d = ((const float4*)sd3[a0 + a])[q0 + kq];
                    acc[a] += d.x * w0_ + d.y * w1_ + d.z * w2_ + d.w * w3_;
                }
            }
        }
        #pragma unroll
        for (int a = 0; a < 4; ++a) {
            float h = sh2[a0 + a][j];
            sd2[a0 + a][j] = acc[a] * h * (1.f - h);
        }
    }

    // ---- bwd: d1 = (W1 @ d2) * h1'. k = t, 8 atoms/thread ----
    {
        float acc[TA];
        #pragma unroll
        for (int a = 0; a < TA; ++a) acc[a] = 0.f;
        for (int c = 0; c < 6; ++c) {
            const int j0 = 24 * c;                // rows of W1T (H2=128 rows)
            const int nrow = (c < 5) ? 24 : 8;
            stage(W1T + j0 * H1, nrow * H1);
            const int q0 = j0 >> 2;
            for (int jq = 0; jq < nrow / 4; ++jq) {
                float w0_ = wbuf[(4 * jq + 0) * H1 + t];
                float w1_ = wbuf[(4 * jq + 1) * H1 + t];
                float w2_ = wbuf[(4 * jq + 2) * H1 + t];
                float w3_ = wbuf[(4 * jq + 3) * H1 + t];
                #pragma unroll
                for (int a = 0; a < TA; ++a) {
                    float4 d = ((const float4*)sd2[a])[q0 + jq];
                    acc[a] += d.x * w0_ + d.y * w1_ + d.z * w2_ + d.w * w3_;
                }
            }
        }
        #pragma unroll
        for (int a = 0; a < TA; ++a) {
            float h = sh1[a][t];
            sd1[a][t] = acc[a] * h * (1.f - h);
        }
    }

    // ---- bwd: dE/dx = W0 @ d1. f = t&63 (<42), 2 atoms/thread ----
    {
        const int f = t & 63, a0 = (t >> 6) * 2;
        float acc[2] = {0.f, 0.f};
        for (int c = 0; c < 2; ++c) {
            const int k0 = (c == 0) ? 0 : 144;    // rows of W0T (H1=256 rows)
            const int nrow = (c == 0) ? 144 : 112;
            stage(W0T + k0 * NFEAT, nrow * NFEAT);
            if (f < NFEAT) {
                const int q0 = k0 >> 2;
                for (int kq = 0; kq < nrow / 4; ++kq) {
                    float w0_ = wbuf[(4 * kq + 0) * NFEAT + f];
                    float w1_ = wbuf[(4 * kq + 1) * NFEAT + f];
                    float w2_ = wbuf[(4 * kq + 2) * NFEAT + f];
                    float w3_ = wbuf[(4 * kq + 3) * NFEAT + f];
                    #pragma unroll
                    for (int a = 0; a < 2; ++a) {
                        float4 d = ((const float4*)sd1[a0 + a])[q0 + kq];
                        acc[a] += d.x * w0_ + d.y * w1_ + d.z * w2_ + d.w * w3_;
                    }
                }
            }
        }
        if (f < NFEAT) {
            #pragma unroll
            for (int a = 0; a < 2; ++a)
                dE[(atom0 + a0 + a) * NFEAT + f] = acc[a];
        }
    }
}

// -------- Kernel 2: Etot[b] = sum_i Ei[b,i] --------
__global__ __launch_bounds__(256) void etot_kernel(const float* __restrict__ Ei,
                                                   float* __restrict__ Etot)
{
    const int b = blockIdx.x;
    const int t = threadIdx.x;
    float v = Ei[b * NA + t] + Ei[b * NA + t + 256];
    __shared__ float red[4];
    #pragma unroll
    for (int off = 32; off > 0; off >>= 1) v += __shfl_down(v, off, 64);
    if ((t & 63) == 0) red[t >> 6] = v;
    __syncthreads();
    if (t == 0) Etot[b] = red[0] + red[1] + red[2] + red[3];
}

// -------- Kernel 3: Force via float4-coalesced dfeat stream (2 streams in flight) --------
__global__ __launch_bounds__(256) void force_kernel(
    const float* __restrict__ dfeat,     // [B,N,M,NFEAT,3] = [bi][100][126]
    const int*   __restrict__ neighbor,  // [B,N,M]
    const float* __restrict__ dE,        // [B,N,NFEAT]
    float* __restrict__ Force)           // [B,N,3]
{
    const int bi = blockIdx.x;
    const int b  = bi >> 9;
    const int t  = threadIdx.x;

    __shared__ int   s_nb[NM];
    __shared__ float s_dE[104 * NFEAT];   // rows 100..103 zero-padded
    __shared__ float s_part[1008];
    __shared__ float s_red[126];

    if (t < NM) s_nb[t] = neighbor[bi * NM + t];
    for (int i = t; i < 4 * NFEAT; i += 256) s_dE[NM * NFEAT + i] = 0.f;
    __syncthreads();

    for (int i = t; i < NM * NFEAT; i += 256) {
        int m = i / NFEAT, f = i - m * NFEAT;
        int n = s_nb[m];
        s_dE[i] = (n > 0) ? dE[((b << 9) + n - 1) * NFEAT + f] : 0.f;
    }
    __syncthreads();

    if (t < 252) {
        const int e4 = 4 * t;
        int off[4];
        #pragma unroll
        for (int c = 0; c < 4; ++c) {
            int ee = e4 + c;
            int r  = ee / 126;
            int e  = ee - r * 126;
            off[c] = r * NFEAT + e / 3;
        }
        const float* base = dfeat + (size_t)bi * (NM * NFEAT * 3);
        float acc[4] = {0.f, 0.f, 0.f, 0.f};

        for (int m0 = 0; m0 < 48; m0 += 8) {
            float4 vA = *(const float4*)(base + m0 * 126 + e4);
            float4 vB = *(const float4*)(base + (m0 + 48) * 126 + e4);
            const float* sdA = s_dE + m0 * NFEAT;
            const float* sdB = s_dE + (m0 + 48) * NFEAT;
            acc[0] += vA.x * sdA[off[0]] + vB.x * sdB[off[0]];
            acc[1] += vA.y * sdA[off[1]] + vB.y * sdB[off[1]];
            acc[2] += vA.z * sdA[off[2]] + vB.z * sdB[off[2]];
            acc[3] += vA.w * sdA[off[3]] + vB.w * sdB[off[3]];
        }
        {   // tail rows 96..103 (rows >= 100 hit zero-padded s_dE)
            const int m0 = 96;
            float vv[4];
            if (bi != NB * NA - 1) {
                float4 v = *(const float4*)(base + m0 * 126 + e4);
                vv[0] = v.x; vv[1] = v.y; vv[2] = v.z; vv[3] = v.w;
            } else {
                #pragma unroll
                for (int c = 0; c < 4; ++c) {
                    int r = (e4 + c) / 126;
                    vv[c] = (m0 + r < NM) ? base[m0 * 126 + e4 + c] : 0.f;
                }
            }
            const float* sd = s_dE + m0 * NFEAT;
            #pragma unroll
            for (int c = 0; c < 4; ++c) acc[c] += vv[c] * sd[off[c]];
        }
        #pragma unroll
        for (int c = 0; c < 4; ++c) s_part[e4 + c] = acc[c];
    }
    __syncthreads();

    if (t < 126) {
        float s = 0.f;
        #pragma unroll
        for (int r = 0; r < 8; ++r) s += s_part[r * 126 + t];
        s_red[t] = s;
    }
    __syncthreads();

    if (t < 3) {
        float s = 0.f;
        #pragma unroll
        for (int f = 0; f < NFEAT; ++f) s += s_red[f * 3 + t];
        Force[bi * 3 + t] = s;
    }
}

extern "C" void kernel_launch(void* const* d_in, const int* in_sizes, int n_in,
                              void* d_out, int out_size, void* d_ws, size_t ws_size,
                              hipStream_t stream) {
    const float* image    = (const float*)d_in[0];
    const float* dfeat    = (const float*)d_in[1];
    const int*   neighbor = (const int*)  d_in[2];
    const float* W0 = (const float*)d_in[3];
    const float* b0 = (const float*)d_in[4];
    const float* W1 = (const float*)d_in[5];
    const float* b1 = (const float*)d_in[6];
    const float* W2 = (const float*)d_in[7];
    const float* b2 = (const float*)d_in[8];
    const float* W3 = (const float*)d_in[9];
    const float* b3 = (const float*)d_in[10];

    float* out   = (float*)d_out;
    float* Etot  = out;                    // [8]
    float* Ei    = out + NB;               // [8*512]
    float* Force = out + NB + NB * NA;     // [8*512*3]

    float* dE  = (float*)d_ws;             // [4096*42]
    float* W0T = dE  + NB * NA * NFEAT;    // [256*42]
    float* W1T = W0T + H1 * NFEAT;         // [128*256]
    float* W2T = W1T + H2 * H1;            // [64*128]

    transpose_weights<<<(H1 * H2 + 255) / 256, 256, 0, stream>>>(W0, W1, W2, W0T, W1T, W2T);
    mlp_fwd_bwd<<<(NB * NA) / TA, 256, 0, stream>>>(image, W0, b0, W1, b1, W2, b2, W3, b3,
                                                    W0T, W1T, W2T, Ei, dE);
    etot_kernel<<<NB, 256, 0, stream>>>(Ei, Etot);
    force_kernel<<<NB * NA, 256, 0, stream>>>(dfeat, neighbor, dE, Force);
}

// Round 5
// 423.196 us; speedup vs baseline: 1.5096x; 1.5096x over previous
//
#include <hip/hip_runtime.h>

#define NFEAT 42
#define H1 256
#define H2 128
#define H3 64
#define NB 8
#define NA 512
#define NM 100
#define NTOT (NB * NA)   // 4096 atoms

__device__ __forceinline__ float sigmoidf(float z) {
    return 1.0f / (1.0f + __expf(-z));
}

// Generic lane=atom matvec tile: acc[j] += sum_k actT[k][n] * WT[(j0+j)*K + k]
// actT reads are lane-coalesced; WT reads are wave-uniform (scalarize to s_load).
template<int K, int JT>
__device__ __forceinline__ void mv(const float* __restrict__ actT,
                                   const float* __restrict__ WT,
                                   int j0, int n, float* __restrict__ acc) {
    static_assert(K % 64 == 0, "K must be a multiple of 64");
    #pragma unroll
    for (int c = 0; c < K / 64; ++c) {
        float act[64];
        #pragma unroll
        for (int i = 0; i < 64; ++i) act[i] = actT[(c * 64 + i) * NTOT + n];
        #pragma unroll
        for (int j = 0; j < JT; ++j) {
            const float* w = WT + (j0 + j) * K + c * 64;
            #pragma unroll
            for (int i = 0; i < 64; ++i) acc[j] += act[i] * w[i];
        }
    }
}

// -------- transpose weights for forward (write-coalesced) --------
__global__ __launch_bounds__(256) void transpose_weights(
    const float* __restrict__ W0, const float* __restrict__ W1, const float* __restrict__ W2,
    float* __restrict__ W0T, float* __restrict__ W1T, float* __restrict__ W2T)
{
    int i = blockIdx.x * 256 + threadIdx.x;
    if (i < H1 * NFEAT) {           // W0T[j][f] = W0[f][j]
        int j = i / NFEAT, f = i - j * NFEAT;
        W0T[i] = W0[f * H1 + j];
    }
    if (i < H2 * H1) {              // W1T[j][k] = W1[k][j]
        int j = i >> 8, k = i & 255;
        W1T[i] = W1[k * H2 + j];
    }
    if (i < H3 * H2) {              // W2T[k][j] = W2[j][k]
        int k = i >> 7, j = i & 127;
        W2T[i] = W2[j * H3 + k];
    }
}

// -------- fwd L0: image[n][42] -> h1T[256][N]. lane=atom, K=42 via LDS --------
__global__ __launch_bounds__(256) void l0_fwd(
    const float* __restrict__ image, const float* __restrict__ W0T,
    const float* __restrict__ b0, float* __restrict__ h1T)
{
    const int t = threadIdx.x;
    const int n0 = blockIdx.x * 256;
    const int j0 = blockIdx.y * 8;

    __shared__ float sx[256 * 43];   // stride 43: conflict-free row reads
    for (int i = t; i < 256 * NFEAT; i += 256) {
        int n = i / NFEAT, f = i - n * NFEAT;
        sx[n * 43 + f] = image[n0 * NFEAT + i];   // coalesced
    }
    __syncthreads();

    float act[NFEAT];
    #pragma unroll
    for (int f = 0; f < NFEAT; ++f) act[f] = sx[t * 43 + f];

    float acc[8];
    #pragma unroll
    for (int j = 0; j < 8; ++j) acc[j] = b0[j0 + j];
    #pragma unroll
    for (int j = 0; j < 8; ++j) {
        const float* w = W0T + (j0 + j) * NFEAT;   // uniform -> s_load
        #pragma unroll
        for (int f = 0; f < NFEAT; ++f) acc[j] += act[f] * w[f];
    }
    const int n = n0 + t;
    #pragma unroll
    for (int j = 0; j < 8; ++j) h1T[(j0 + j) * NTOT + n] = sigmoidf(acc[j]);
}

// -------- fwd L1: h1T -> h2T. K=256, JT=8 --------
__global__ __launch_bounds__(256) void l1_fwd(
    const float* __restrict__ h1T, const float* __restrict__ W1T,
    const float* __restrict__ b1, float* __restrict__ h2T)
{
    const int n = blockIdx.x * 256 + threadIdx.x;
    const int j0 = blockIdx.y * 8;
    float acc[8];
    #pragma unroll
    for (int j = 0; j < 8; ++j) acc[j] = b1[j0 + j];
    mv<H1, 8>(h1T, W1T, j0, n, acc);
    #pragma unroll
    for (int j = 0; j < 8; ++j) h2T[(j0 + j) * NTOT + n] = sigmoidf(acc[j]);
}

// -------- fwd L2: h2T -> h3T. K=128, JT=4 --------
__global__ __launch_bounds__(256) void l2_fwd(
    const float* __restrict__ h2T, const float* __restrict__ W2T,
    const float* __restrict__ b2, float* __restrict__ h3T)
{
    const int n = blockIdx.x * 256 + threadIdx.x;
    const int j0 = blockIdx.y * 4;
    float acc[4];
    #pragma unroll
    for (int j = 0; j < 4; ++j) acc[j] = b2[j0 + j];
    mv<H2, 4>(h2T, W2T, j0, n, acc);
    #pragma unroll
    for (int j = 0; j < 4; ++j) h3T[(j0 + j) * NTOT + n] = sigmoidf(acc[j]);
}

// -------- L3 + Ei + d3: Ei[n] = W3.h3 + b3 ; d3T[k][n] = W3[k] h3 (1-h3) --------
__global__ __launch_bounds__(256) void l3_ei(
    const float* __restrict__ h3T, const float* __restrict__ W3,
    const float* __restrict__ b3, float* __restrict__ Ei, float* __restrict__ d3T)
{
    const int n = blockIdx.x * 256 + threadIdx.x;
    float e = b3[0];
    #pragma unroll
    for (int k = 0; k < H3; ++k) {
        float w = W3[k];                     // uniform
        float h = h3T[k * NTOT + n];
        e += w * h;
        d3T[k * NTOT + n] = w * h * (1.f - h);
    }
    Ei[n] = e;
}

// -------- bwd: d2T[j][n] = (sum_k W2[j][k] d3[k]) * h2'(j) . K=64, JT=4 --------
__global__ __launch_bounds__(256) void bwd_d2(
    const float* __restrict__ d3T, const float* __restrict__ W2,
    const float* __restrict__ h2T, float* __restrict__ d2T)
{
    const int n = blockIdx.x * 256 + threadIdx.x;
    const int j0 = blockIdx.y * 4;
    float acc[4] = {0.f, 0.f, 0.f, 0.f};
    mv<H3, 4>(d3T, W2, j0, n, acc);          // W2 row j contiguous in k
    #pragma unroll
    for (int j = 0; j < 4; ++j) {
        float h = h2T[(j0 + j) * NTOT + n];
        d2T[(j0 + j) * NTOT + n] = acc[j] * h * (1.f - h);
    }
}

// -------- bwd: d1T[k][n] = (sum_j W1[k][j] d2[j]) * h1'(k) . K=128, JT=8 --------
__global__ __launch_bounds__(256) void bwd_d1(
    const float* __restrict__ d2T, const float* __restrict__ W1,
    const float* __restrict__ h1T, float* __restrict__ d1T)
{
    const int n = blockIdx.x * 256 + threadIdx.x;
    const int j0 = blockIdx.y * 8;
    float acc[8] = {0.f, 0.f, 0.f, 0.f, 0.f, 0.f, 0.f, 0.f};
    mv<H2, 8>(d2T, W1, j0, n, acc);          // W1 row k contiguous in j
    #pragma unroll
    for (int j = 0; j < 8; ++j) {
        float h = h1T[(j0 + j) * NTOT + n];
        d1T[(j0 + j) * NTOT + n] = acc[j] * h * (1.f - h);
    }
}

// -------- bwd: dE[n][f] = sum_k W0[f][k] d1[k] . K=256, JT=14 --------
__global__ __launch_bounds__(256) void bwd_dE(
    const float* __restrict__ d1T, const float* __restrict__ W0,
    float* __restrict__ dE)
{
    const int n = blockIdx.x * 256 + threadIdx.x;
    const int f0 = blockIdx.y * 14;
    float acc[14];
    #pragma unroll
    for (int j = 0; j < 14; ++j) acc[j] = 0.f;
    mv<H1, 14>(d1T, W0, f0, n, acc);         // W0 row f contiguous in k
    #pragma unroll
    for (int j = 0; j < 14; ++j) dE[n * NFEAT + f0 + j] = acc[j];
}

// -------- Etot[b] = sum_i Ei[b,i] --------
__global__ __launch_bounds__(256) void etot_kernel(const float* __restrict__ Ei,
                                                   float* __restrict__ Etot)
{
    const int b = blockIdx.x;
    const int t = threadIdx.x;
    float v = Ei[b * NA + t] + Ei[b * NA + t + 256];
    __shared__ float red[4];
    #pragma unroll
    for (int off = 32; off > 0; off >>= 1) v += __shfl_down(v, off, 64);
    if ((t & 63) == 0) red[t >> 6] = v;
    __syncthreads();
    if (t == 0) Etot[b] = red[0] + red[1] + red[2] + red[3];
}

// -------- Force: float4-coalesced dfeat stream, gathered dE in LDS --------
__global__ __launch_bounds__(256) void force_kernel(
    const float* __restrict__ dfeat,     // [bi][100][126]
    const int*   __restrict__ neighbor,  // [B,N,M]
    const float* __restrict__ dE,        // [B*N, 42]
    float* __restrict__ Force)           // [B,N,3]
{
    const int bi = blockIdx.x;
    const int b  = bi >> 9;
    const int t  = threadIdx.x;

    __shared__ int   s_nb[NM];
    __shared__ float s_dE[104 * NFEAT];   // rows 100..103 zero-padded
    __shared__ float s_part[1008];
    __shared__ float s_red[126];

    if (t < NM) s_nb[t] = neighbor[bi * NM + t];
    for (int i = t; i < 4 * NFEAT; i += 256) s_dE[NM * NFEAT + i] = 0.f;
    __syncthreads();

    for (int i = t; i < NM * NFEAT; i += 256) {
        int m = i / NFEAT, f = i - m * NFEAT;
        int n = s_nb[m];
        s_dE[i] = (n > 0) ? dE[((b << 9) + n - 1) * NFEAT + f] : 0.f;
    }
    __syncthreads();

    if (t < 252) {
        const int e4 = 4 * t;
        int off[4];
        #pragma unroll
        for (int c = 0; c < 4; ++c) {
            int ee = e4 + c;
            int r  = ee / 126;
            int e  = ee - r * 126;
            off[c] = r * NFEAT + e / 3;
        }
        const float* base = dfeat + (size_t)bi * (NM * NFEAT * 3);
        float acc[4] = {0.f, 0.f, 0.f, 0.f};

        for (int m0 = 0; m0 < 48; m0 += 8) {
            float4 vA = *(const float4*)(base + m0 * 126 + e4);
            float4 vB = *(const float4*)(base + (m0 + 48) * 126 + e4);
            const float* sdA = s_dE + m0 * NFEAT;
            const float* sdB = s_dE + (m0 + 48) * NFEAT;
            acc[0] += vA.x * sdA[off[0]] + vB.x * sdB[off[0]];
            acc[1] += vA.y * sdA[off[1]] + vB.y * sdB[off[1]];
            acc[2] += vA.z * sdA[off[2]] + vB.z * sdB[off[2]];
            acc[3] += vA.w * sdA[off[3]] + vB.w * sdB[off[3]];
        }
        {   // tail rows 96..103 (>=100 hit zero-padded s_dE)
            const int m0 = 96;
            float vv[4];
            if (bi != NTOT - 1) {
                float4 v = *(const float4*)(base + m0 * 126 + e4);
                vv[0] = v.x; vv[1] = v.y; vv[2] = v.z; vv[3] = v.w;
            } else {
                #pragma unroll
                for (int c = 0; c < 4; ++c) {
                    int r = (e4 + c) / 126;
                    vv[c] = (m0 + r < NM) ? base[m0 * 126 + e4 + c] : 0.f;
                }
            }
            const float* sd = s_dE + m0 * NFEAT;
            #pragma unroll
            for (int c = 0; c < 4; ++c) acc[c] += vv[c] * sd[off[c]];
        }
        #pragma unroll
        for (int c = 0; c < 4; ++c) s_part[e4 + c] = acc[c];
    }
    __syncthreads();

    if (t < 126) {
        float s = 0.f;
        #pragma unroll
        for (int r = 0; r < 8; ++r) s += s_part[r * 126 + t];
        s_red[t] = s;
    }
    __syncthreads();

    if (t < 3) {
        float s = 0.f;
        #pragma unroll
        for (int f = 0; f < NFEAT; ++f) s += s_red[f * 3 + t];
        Force[bi * 3 + t] = s;
    }
}

extern "C" void kernel_launch(void* const* d_in, const int* in_sizes, int n_in,
                              void* d_out, int out_size, void* d_ws, size_t ws_size,
                              hipStream_t stream) {
    const float* image    = (const float*)d_in[0];
    const float* dfeat    = (const float*)d_in[1];
    const int*   neighbor = (const int*)  d_in[2];
    const float* W0 = (const float*)d_in[3];
    const float* b0 = (const float*)d_in[4];
    const float* W1 = (const float*)d_in[5];
    const float* b1 = (const float*)d_in[6];
    const float* W2 = (const float*)d_in[7];
    const float* b2 = (const float*)d_in[8];
    const float* W3 = (const float*)d_in[9];
    const float* b3 = (const float*)d_in[10];

    float* out   = (float*)d_out;
    float* Etot  = out;                    // [8]
    float* Ei    = out + NB;               // [4096]
    float* Force = out + NB + NTOT;        // [4096*3]

    float* p   = (float*)d_ws;
    float* dE  = p;  p += NTOT * NFEAT;    // [4096][42]
    float* W0T = p;  p += H1 * NFEAT;
    float* W1T = p;  p += H2 * H1;
    float* W2T = p;  p += H3 * H2;
    float* h1T = p;  p += H1 * NTOT;
    float* h2T = p;  p += H2 * NTOT;
    float* h3T = p;  p += H3 * NTOT;
    float* d3T = p;  p += H3 * NTOT;
    float* d2T = p;  p += H2 * NTOT;
    float* d1T = p;  p += H1 * NTOT;

    transpose_weights<<<(H1 * H2 + 255) / 256, 256, 0, stream>>>(W0, W1, W2, W0T, W1T, W2T);
    l0_fwd <<<dim3(16, 32), 256, 0, stream>>>(image, W0T, b0, h1T);
    l1_fwd <<<dim3(16, 16), 256, 0, stream>>>(h1T, W1T, b1, h2T);
    l2_fwd <<<dim3(16, 16), 256, 0, stream>>>(h2T, W2T, b2, h3T);
    l3_ei  <<<16, 256, 0, stream>>>(h3T, W3, b3, Ei, d3T);
    bwd_d2 <<<dim3(16, 32), 256, 0, stream>>>(d3T, W2, h2T, d2T);
    bwd_d1 <<<dim3(16, 32), 256, 0, stream>>>(d2T, W1, h1T, d1T);
    bwd_dE <<<dim3(16, 3),  256, 0, stream>>>(d1T, W0, dE);
    etot_kernel <<<NB, 256, 0, stream>>>(Ei, Etot);
    force_kernel<<<NTOT, 256, 0, stream>>>(dfeat, neighbor, dE, Force);
}

// Round 6
// 366.674 us; speedup vs baseline: 1.7423x; 1.1541x over previous
//
#include <hip/hip_runtime.h>

#define NFEAT 42
#define H1 256
#define H2 128
#define H3 64
#define NB 8
#define NA 512
#define NM 100
#define NTOT (NB * NA)
#define TA 8   // atoms per MLP block (512 blocks)

__device__ __forceinline__ float sigmoidf(float z) {
    return 1.0f / (1.0f + __expf(-z));
}

// -------- Kernel 0: transposed weight copies (for coalesced bwd) --------
__global__ __launch_bounds__(256) void transpose_weights(
    const float* __restrict__ W0, const float* __restrict__ W1, const float* __restrict__ W2,
    float* __restrict__ W0T, float* __restrict__ W1T, float* __restrict__ W2T)
{
    int i = blockIdx.x * 256 + threadIdx.x;
    if (i < H1 * NFEAT) {           // W0T[k][f] = W0[f][k]   [256][42]
        int k = i / NFEAT, f = i - k * NFEAT;
        W0T[i] = W0[f * H1 + k];
    }
    if (i < H2 * H1) {              // W1T[j][k] = W1[k][j]   [128][256]
        int j = i >> 8, k = i & 255;
        W1T[i] = W1[k * H2 + j];
    }
    if (i < H3 * H2) {              // W2T[k][j] = W2[j][k]   [64][128]
        int k = i >> 7, j = i & 127;
        W2T[i] = W2[j * H3 + k];
    }
}

// -------- Kernel 1: monolithic per-8-atom MLP fwd+bwd, float4 weight loads --------
__global__ __launch_bounds__(256) void mlp_fwd_bwd(
    const float* __restrict__ image,
    const float* __restrict__ W0, const float* __restrict__ b0,
    const float* __restrict__ W1, const float* __restrict__ b1,
    const float* __restrict__ W2, const float* __restrict__ b2,
    const float* __restrict__ W3, const float* __restrict__ b3,
    const float* __restrict__ W0T, const float* __restrict__ W1T, const float* __restrict__ W2T,
    float* __restrict__ Ei, float* __restrict__ dE)
{
    const int t = threadIdx.x;
    const int atom0 = blockIdx.x * TA;

    __shared__ __align__(16) float sx[TA][NFEAT + 2];
    __shared__ __align__(16) float sh1[TA][H1];
    __shared__ __align__(16) float sh2[TA][H2];
    __shared__ __align__(16) float sh3[TA][H3];
    __shared__ __align__(16) float sd3[TA][H3];
    __shared__ __align__(16) float sd2[TA][H2];
    __shared__ __align__(16) float sd1[TA][H1];

    for (int i = t; i < TA * NFEAT; i += 256) {
        int a = i / NFEAT, f = i - a * NFEAT;
        sx[a][f] = image[(atom0 + a) * NFEAT + f];
    }
    __syncthreads();

    // ---- L0: 42 -> 256. jj = t&63 -> j = 4*jj; g = t>>6 -> atoms 2g,2g+1 ----
    {
        const int jj = t & 63, g = t >> 6;
        const int a0 = 2 * g, a1 = 2 * g + 1;
        float4 acc0 = {0.f, 0.f, 0.f, 0.f}, acc1 = {0.f, 0.f, 0.f, 0.f};
        for (int k = 0; k < NFEAT; ++k) {
            float4 w = *(const float4*)&W0[k * H1 + 4 * jj];
            float x0 = sx[a0][k], x1 = sx[a1][k];
            acc0.x += x0 * w.x; acc0.y += x0 * w.y; acc0.z += x0 * w.z; acc0.w += x0 * w.w;
            acc1.x += x1 * w.x; acc1.y += x1 * w.y; acc1.z += x1 * w.z; acc1.w += x1 * w.w;
        }
        float4 bb = *(const float4*)&b0[4 * jj];
        float4 o0 = {sigmoidf(acc0.x + bb.x), sigmoidf(acc0.y + bb.y),
                     sigmoidf(acc0.z + bb.z), sigmoidf(acc0.w + bb.w)};
        float4 o1 = {sigmoidf(acc1.x + bb.x), sigmoidf(acc1.y + bb.y),
                     sigmoidf(acc1.z + bb.z), sigmoidf(acc1.w + bb.w)};
        *(float4*)&sh1[a0][4 * jj] = o0;
        *(float4*)&sh1[a1][4 * jj] = o1;
    }
    __syncthreads();

    // ---- L1: 256 -> 128. jj = t&31 -> j = 4*jj; a = t>>5 ----
    {
        const int jj = t & 31, a = t >> 5;
        float4 acc = {0.f, 0.f, 0.f, 0.f};
        #pragma unroll 4
        for (int k = 0; k < H1; ++k) {
            float4 w = *(const float4*)&W1[k * H2 + 4 * jj];
            float h = sh1[a][k];
            acc.x += h * w.x; acc.y += h * w.y; acc.z += h * w.z; acc.w += h * w.w;
        }
        float4 bb = *(const float4*)&b1[4 * jj];
        float4 o = {sigmoidf(acc.x + bb.x), sigmoidf(acc.y + bb.y),
                    sigmoidf(acc.z + bb.z), sigmoidf(acc.w + bb.w)};
        *(float4*)&sh2[a][4 * jj] = o;
    }
    __syncthreads();

    // ---- L2: 128 -> 64. t<128: jj = t&15 -> j = 4*jj; a = t>>4 ----
    if (t < 128) {
        const int jj = t & 15, a = t >> 4;
        float4 acc = {0.f, 0.f, 0.f, 0.f};
        #pragma unroll 4
        for (int k = 0; k < H2; ++k) {
            float4 w = *(const float4*)&W2[k * H3 + 4 * jj];
            float h = sh2[a][k];
            acc.x += h * w.x; acc.y += h * w.y; acc.z += h * w.z; acc.w += h * w.w;
        }
        float4 bb = *(const float4*)&b2[4 * jj];
        float4 o = {sigmoidf(acc.x + bb.x), sigmoidf(acc.y + bb.y),
                    sigmoidf(acc.z + bb.z), sigmoidf(acc.w + bb.w)};
        *(float4*)&sh3[a][4 * jj] = o;
    }
    __syncthreads();

    // ---- output 64 -> 1 (linear) + sd3. wave w: atoms 2w, 2w+1 ----
    {
        const int lane = t & 63, a0 = (t >> 6) * 2;
        float w = W3[lane];
        float bb = b3[0];
        #pragma unroll
        for (int a = a0; a < a0 + 2; ++a) {
            float h = sh3[a][lane];
            sd3[a][lane] = w * h * (1.f - h);
            float v = w * h;
            #pragma unroll
            for (int off = 32; off > 0; off >>= 1) v += __shfl_down(v, off, 64);
            if (lane == 0) Ei[atom0 + a] = v + bb;
        }
    }
    __syncthreads();

    // ---- bwd d2: jj = t&31 -> j = 4*jj; a = t>>5. sum_k W2T[k][j] d3[k] ----
    {
        const int jj = t & 31, a = t >> 5;
        float4 acc = {0.f, 0.f, 0.f, 0.f};
        #pragma unroll 4
        for (int k = 0; k < H3; ++k) {
            float4 w = *(const float4*)&W2T[k * H2 + 4 * jj];
            float d = sd3[a][k];
            acc.x += d * w.x; acc.y += d * w.y; acc.z += d * w.z; acc.w += d * w.w;
        }
        float4 h = *(const float4*)&sh2[a][4 * jj];
        float4 o = {acc.x * h.x * (1.f - h.x), acc.y * h.y * (1.f - h.y),
                    acc.z * h.z * (1.f - h.z), acc.w * h.w * (1.f - h.w)};
        *(float4*)&sd2[a][4 * jj] = o;
    }
    __syncthreads();

    // ---- bwd d1: kk = t&63 -> k = 4*kk; g = t>>6 -> atoms 2g,2g+1 ----
    {
        const int kk = t & 63, g = t >> 6;
        const int a0 = 2 * g, a1 = 2 * g + 1;
        float4 acc0 = {0.f, 0.f, 0.f, 0.f}, acc1 = {0.f, 0.f, 0.f, 0.f};
        #pragma unroll 4
        for (int j = 0; j < H2; ++j) {
            float4 w = *(const float4*)&W1T[j * H1 + 4 * kk];
            float d0 = sd2[a0][j], d1v = sd2[a1][j];
            acc0.x += d0 * w.x; acc0.y += d0 * w.y; acc0.z += d0 * w.z; acc0.w += d0 * w.w;
            acc1.x += d1v * w.x; acc1.y += d1v * w.y; acc1.z += d1v * w.z; acc1.w += d1v * w.w;
        }
        float4 h0 = *(const float4*)&sh1[a0][4 * kk];
        float4 h1v = *(const float4*)&sh1[a1][4 * kk];
        float4 o0 = {acc0.x * h0.x * (1.f - h0.x), acc0.y * h0.y * (1.f - h0.y),
                     acc0.z * h0.z * (1.f - h0.z), acc0.w * h0.w * (1.f - h0.w)};
        float4 o1 = {acc1.x * h1v.x * (1.f - h1v.x), acc1.y * h1v.y * (1.f - h1v.y),
                     acc1.z * h1v.z * (1.f - h1v.z), acc1.w * h1v.w * (1.f - h1v.w)};
        *(float4*)&sd1[a0][4 * kk] = o0;
        *(float4*)&sd1[a1][4 * kk] = o1;
    }
    __syncthreads();

    // ---- bwd dE: f = t&63 (<42); g = t>>6 -> atoms 2g,2g+1 ----
    {
        const int f = t & 63, g = t >> 6;
        if (f < NFEAT) {
            const int a0 = 2 * g, a1 = 2 * g + 1;
            float acc0 = 0.f, acc1 = 0.f;
            #pragma unroll 4
            for (int k = 0; k < H1; ++k) {
                float w = W0T[k * NFEAT + f];
                acc0 += sd1[a0][k] * w;
                acc1 += sd1[a1][k] * w;
            }
            dE[(atom0 + a0) * NFEAT + f] = acc0;
            dE[(atom0 + a1) * NFEAT + f] = acc1;
        }
    }
}

// -------- Kernel 2: Etot --------
__global__ __launch_bounds__(256) void etot_kernel(const float* __restrict__ Ei,
                                                   float* __restrict__ Etot)
{
    const int b = blockIdx.x;
    const int t = threadIdx.x;
    float v = Ei[b * NA + t] + Ei[b * NA + t + 256];
    __shared__ float red[4];
    #pragma unroll
    for (int off = 32; off > 0; off >>= 1) v += __shfl_down(v, off, 64);
    if ((t & 63) == 0) red[t >> 6] = v;
    __syncthreads();
    if (t == 0) Etot[b] = red[0] + red[1] + red[2] + red[3];
}

// -------- Kernel 3: Force — 12 float4 loads in flight, then FMA --------
__global__ __launch_bounds__(256) void force_kernel(
    const float* __restrict__ dfeat,     // [bi][100][126]
    const int*   __restrict__ neighbor,
    const float* __restrict__ dE,        // [B*N, 42]
    float* __restrict__ Force)
{
    const int bi = blockIdx.x;
    const int b  = bi >> 9;
    const int t  = threadIdx.x;

    __shared__ int   s_nb[NM];
    __shared__ float s_dE[104 * NFEAT];   // rows 100..103 zero-padded
    __shared__ float s_part[1008];
    __shared__ float s_red[126];

    if (t < NM) s_nb[t] = neighbor[bi * NM + t];
    for (int i = t; i < 4 * NFEAT; i += 256) s_dE[NM * NFEAT + i] = 0.f;
    __syncthreads();

    for (int i = t; i < NM * NFEAT; i += 256) {
        int m = i / NFEAT, f = i - m * NFEAT;
        int n = s_nb[m];
        s_dE[i] = (n > 0) ? dE[((b << 9) + n - 1) * NFEAT + f] : 0.f;
    }
    __syncthreads();

    if (t < 252) {
        const int e4 = 4 * t;
        int off[4];
        #pragma unroll
        for (int c = 0; c < 4; ++c) {
            int ee = e4 + c;
            int r  = ee / 126;
            int e  = ee - r * 126;
            off[c] = r * NFEAT + e / 3;
        }
        const float* base = dfeat + (size_t)bi * (NM * NFEAT * 3);
        float acc[4] = {0.f, 0.f, 0.f, 0.f};

        // rows 0..95: issue all 12 loads, then consume
        float4 v[12];
        #pragma unroll
        for (int u = 0; u < 6; ++u) {
            v[2 * u]     = *(const float4*)(base + (u * 8) * 126 + e4);
            v[2 * u + 1] = *(const float4*)(base + (u * 8 + 48) * 126 + e4);
        }
        #pragma unroll
        for (int u = 0; u < 6; ++u) {
            const float* sdA = s_dE + (u * 8) * NFEAT;
            const float* sdB = s_dE + (u * 8 + 48) * NFEAT;
            acc[0] += v[2 * u].x * sdA[off[0]] + v[2 * u + 1].x * sdB[off[0]];
            acc[1] += v[2 * u].y * sdA[off[1]] + v[2 * u + 1].y * sdB[off[1]];
            acc[2] += v[2 * u].z * sdA[off[2]] + v[2 * u + 1].z * sdB[off[2]];
            acc[3] += v[2 * u].w * sdA[off[3]] + v[2 * u + 1].w * sdB[off[3]];
        }
        {   // tail rows 96..103 (>=100 hit zero-padded s_dE)
            const int m0 = 96;
            float vv[4];
            if (bi != NTOT - 1) {
                float4 w = *(const float4*)(base + m0 * 126 + e4);
                vv[0] = w.x; vv[1] = w.y; vv[2] = w.z; vv[3] = w.w;
            } else {
                #pragma unroll
                for (int c = 0; c < 4; ++c) {
                    int r = (e4 + c) / 126;
                    vv[c] = (m0 + r < NM) ? base[m0 * 126 + e4 + c] : 0.f;
                }
            }
            const float* sd = s_dE + m0 * NFEAT;
            #pragma unroll
            for (int c = 0; c < 4; ++c) acc[c] += vv[c] * sd[off[c]];
        }
        #pragma unroll
        for (int c = 0; c < 4; ++c) s_part[e4 + c] = acc[c];
    }
    __syncthreads();

    if (t < 126) {
        float s = 0.f;
        #pragma unroll
        for (int r = 0; r < 8; ++r) s += s_part[r * 126 + t];
        s_red[t] = s;
    }
    __syncthreads();

    if (t < 3) {
        float s = 0.f;
        #pragma unroll
        for (int f = 0; f < NFEAT; ++f) s += s_red[f * 3 + t];
        Force[bi * 3 + t] = s;
    }
}

extern "C" void kernel_launch(void* const* d_in, const int* in_sizes, int n_in,
                              void* d_out, int out_size, void* d_ws, size_t ws_size,
                              hipStream_t stream) {
    const float* image    = (const float*)d_in[0];
    const float* dfeat    = (const float*)d_in[1];
    const int*   neighbor = (const int*)  d_in[2];
    const float* W0 = (const float*)d_in[3];
    const float* b0 = (const float*)d_in[4];
    const float* W1 = (const float*)d_in[5];
    const float* b1 = (const float*)d_in[6];
    const float* W2 = (const float*)d_in[7];
    const float* b2 = (const float*)d_in[8];
    const float* W3 = (const float*)d_in[9];
    const float* b3 = (const float*)d_in[10];

    float* out   = (float*)d_out;
    float* Etot  = out;
    float* Ei    = out + NB;
    float* Force = out + NB + NTOT;

    float* dE  = (float*)d_ws;             // [4096][42]
    float* W0T = dE  + NTOT * NFEAT;       // [256][42]
    float* W1T = W0T + H1 * NFEAT;         // [128][256]
    float* W2T = W1T + H2 * H1;            // [64][128]

    transpose_weights<<<(H1 * H2 + 255) / 256, 256, 0, stream>>>(W0, W1, W2, W0T, W1T, W2T);
    mlp_fwd_bwd<<<NTOT / TA, 256, 0, stream>>>(image, W0, b0, W1, b1, W2, b2, W3, b3,
                                               W0T, W1T, W2T, Ei, dE);
    etot_kernel<<<NB, 256, 0, stream>>>(Ei, Etot);
    force_kernel<<<NTOT, 256, 0, stream>>>(dfeat, neighbor, dE, Force);
}